// Round 7
// baseline (279.359 us; speedup 1.0000x reference)
//
#include <hip/hip_runtime.h>

#define N_DIM 8192   // rows of features / columns of w / output length
#define K_DIM 512    // inner dim of features @ E
#define D_DIM 4096   // columns of E / rows of w

typedef __bf16 bf16x8 __attribute__((ext_vector_type(8)));
typedef float  f32x16 __attribute__((ext_vector_type(16)));
typedef float  f32x4v __attribute__((ext_vector_type(4)));
typedef unsigned short u16x8 __attribute__((ext_vector_type(8)));

__device__ __forceinline__ unsigned short f2bf(float f) {
    union { float f; unsigned int u; } v; v.f = f;
    unsigned int r = v.u + 0x7FFF + ((v.u >> 16) & 1);   // RNE
    return (unsigned short)(r >> 16);
}

// ---------------------------------------------------------------------------
// Kernel 1: E [512][4096] f32  ->  ET [4096][512] bf16 (k-contiguous rows)
// ---------------------------------------------------------------------------
__global__ __launch_bounds__(256) void transpose_E(const float* __restrict__ E,
                                                   unsigned short* __restrict__ ET) {
    __shared__ float tile[64][65];
    const int d0 = blockIdx.x * 64;
    const int k0 = blockIdx.y * 64;
    const int tid = threadIdx.x;
    const int r  = tid / 16;          // 0..15
    const int c4 = (tid % 16) * 4;    // 0..60
#pragma unroll
    for (int p = 0; p < 4; ++p) {
        int k = p * 16 + r;
        float4 v = *reinterpret_cast<const float4*>(E + (size_t)(k0 + k) * D_DIM + d0 + c4);
        tile[k][c4 + 0] = v.x; tile[k][c4 + 1] = v.y;
        tile[k][c4 + 2] = v.z; tile[k][c4 + 3] = v.w;
    }
    __syncthreads();
#pragma unroll
    for (int p = 0; p < 4; ++p) {
        int d = p * 16 + r;
        ushort4 o;
        o.x = f2bf(tile[c4 + 0][d]);
        o.y = f2bf(tile[c4 + 1][d]);
        o.z = f2bf(tile[c4 + 2][d]);
        o.w = f2bf(tile[c4 + 3][d]);
        *reinterpret_cast<ushort4*>(ET + (size_t)(d0 + d) * K_DIM + k0 + c4) = o;
    }
}

// ---------------------------------------------------------------------------
// Kernel 2: F [8192][512] f32 -> FB bf16, same layout (k-contiguous rows)
// ---------------------------------------------------------------------------
__global__ __launch_bounds__(256) void convert_F(const float* __restrict__ F,
                                                 unsigned short* __restrict__ FB) {
    const int idx8 = (blockIdx.x * 256 + threadIdx.x) * 8;
    float4 a = *reinterpret_cast<const float4*>(F + idx8);
    float4 b = *reinterpret_cast<const float4*>(F + idx8 + 4);
    u16x8 o;
    o[0] = f2bf(a.x); o[1] = f2bf(a.y); o[2] = f2bf(a.z); o[3] = f2bf(a.w);
    o[4] = f2bf(b.x); o[5] = f2bf(b.y); o[6] = f2bf(b.z); o[7] = f2bf(b.w);
    *reinterpret_cast<u16x8*>(FB + idx8) = o;
}

// ---------------------------------------------------------------------------
// Kernel 3: fused  out[n] = sum_d (F@E + b)[n,d] * w[d,n], computed as y^T.
// R4 main loop: 128(d) x 128(n) tile, BK=64, 4 waves (2x2), 32x32x16 MFMA,
// source-side XOR chunk swizzle, XCD-rectangle block swizzle.
// R6 epilogue: stage y(+bias) f32 into the freed 32 KB LDS (two 64-d halves);
// each lane reads y via ds_read_b128 and W via nontemporal f32x4v
// (512 B/wave segments, 4x fewer mem insts than scalar dwords),
// accumulating 4 n-columns; d-reduction via 4 KB LDS; 128 atomics/block.
// ---------------------------------------------------------------------------
__global__ __launch_bounds__(256) void gemm_fused(const unsigned short* __restrict__ FB,
                                                  const float* __restrict__ W,
                                                  const unsigned short* __restrict__ ET,
                                                  const float* __restrict__ B,
                                                  float* __restrict__ out) {
    __shared__ __align__(16) unsigned char smem[32768];
    unsigned short* Ash = (unsigned short*)smem;            // 16 KB: 2 panels x 128 x 32
    unsigned short* Bsh = (unsigned short*)(smem + 16384);  // 16 KB
    float* ybuf = (float*)smem;                             // epilogue reuse: 64 x 128 f32

    const int tid  = threadIdx.x;
    const int wave = tid >> 6;
    const int lane = tid & 63;
    const int wy   = wave >> 1;     // d-direction wave coord (0..1)
    const int wx   = wave & 1;      // n-direction wave coord (0..1)
    const int l31  = lane & 31;
    const int half = lane >> 5;

    // --- XCD-rectangle swizzle (bijection on 64x32 tile grid) ---
    const int f   = blockIdx.x + ((int)gridDim.x) * blockIdx.y;
    const int xcd = f & 7;
    const int s   = f >> 3;                        // 0..255 within XCD
    const int ntile = (xcd & 3) * 16 + (s & 15);   // 0..63
    const int dtile = (xcd >> 2) * 16 + (s >> 4);  // 0..31
    const int n0 = ntile * 128;
    const int d0 = dtile * 128;

    f32x16 acc[2][2] = {};   // [mi=d-tile][ni=n-tile]

    // staging: one global_load_lds(16B) covers 16 rows x 64 B
    const int srow   = lane >> 2;                               // 0..15
    const int schunk = (((lane & 3) ^ ((srow >> 1) & 3)) * 8);  // swizzled chunk (shorts)

    for (int kt = 0; kt < K_DIM / 64; ++kt) {
        const int kb = kt * 64;
#pragma unroll
        for (int p = 0; p < 2; ++p) {
#pragma unroll
            for (int jj = 0; jj < 2; ++jj) {
                const int j = wave * 2 + jj;   // 0..7 -> 16 rows each
                const unsigned short* ga =
                    ET + (size_t)(d0 + j * 16 + srow) * K_DIM + kb + p * 32 + schunk;
                __builtin_amdgcn_global_load_lds(
                    (const __attribute__((address_space(1))) void*)ga,
                    (__attribute__((address_space(3))) void*)(Ash + p * 4096 + j * 512),
                    16, 0, 0);
                const unsigned short* gb =
                    FB + (size_t)(n0 + j * 16 + srow) * K_DIM + kb + p * 32 + schunk;
                __builtin_amdgcn_global_load_lds(
                    (const __attribute__((address_space(1))) void*)gb,
                    (__attribute__((address_space(3))) void*)(Bsh + p * 4096 + j * 512),
                    16, 0, 0);
            }
        }
        __syncthreads();

#pragma unroll
        for (int ks = 0; ks < 4; ++ks) {
            const int p = ks >> 1;
            const int c = (ks & 1) * 2 + half;   // 16B chunk index within row
            bf16x8 af[2], bf[2];
#pragma unroll
            for (int mi = 0; mi < 2; ++mi) {
                const int R = wy * 64 + mi * 32 + l31;
                const int slot = c ^ ((R >> 1) & 3);
                af[mi] = *reinterpret_cast<const bf16x8*>(
                    Ash + p * 4096 + R * 32 + slot * 8);
            }
#pragma unroll
            for (int ni = 0; ni < 2; ++ni) {
                const int R = wx * 64 + ni * 32 + l31;
                const int slot = c ^ ((R >> 1) & 3);
                bf[ni] = *reinterpret_cast<const bf16x8*>(
                    Bsh + p * 4096 + R * 32 + slot * 8);
            }
#pragma unroll
            for (int mi = 0; mi < 2; ++mi)
#pragma unroll
                for (int ni = 0; ni < 2; ++ni)
                    acc[mi][ni] = __builtin_amdgcn_mfma_f32_32x32x16_bf16(
                        af[mi], bf[ni], acc[mi][ni], 0, 0, 0);
        }
        __syncthreads();
    }

    // --- epilogue ---
    // C layout 32x32: col(n)=lane&31, row(d-local)= mi*32 + 4*half + (reg&3) + 8*(reg>>2)
    const int n4  = (tid & 31) * 4;   // 4 n-columns owned by this thread
    const int dsb = tid >> 5;         // 0..7: d-sub-slice
    float part[4] = {0.f, 0.f, 0.f, 0.f};

#pragma unroll
    for (int h = 0; h < 2; ++h) {
        __syncthreads();   // ybuf free (after main loop / previous half consumed)
        if (wy == h) {
#pragma unroll
            for (int mi = 0; mi < 2; ++mi) {
#pragma unroll
                for (int reg = 0; reg < 16; ++reg) {
                    const int dl = mi * 32 + 4 * half + (reg & 3) + 8 * (reg >> 2);
                    const float bd = B[d0 + h * 64 + dl];
#pragma unroll
                    for (int ni = 0; ni < 2; ++ni)
                        ybuf[dl * 128 + wx * 64 + ni * 32 + l31] = acc[mi][ni][reg] + bd;
                }
            }
        }
        __syncthreads();
#pragma unroll
        for (int i = 0; i < 8; ++i) {
            const int dl = dsb + 8 * i;
            const float4 yv = *reinterpret_cast<const float4*>(ybuf + dl * 128 + n4);
            const f32x4v* wp = reinterpret_cast<const f32x4v*>(
                W + (size_t)(d0 + h * 64 + dl) * N_DIM + n0 + n4);
            const f32x4v wv = __builtin_nontemporal_load(wp);
            part[0] += yv.x * wv[0];
            part[1] += yv.y * wv[1];
            part[2] += yv.z * wv[2];
            part[3] += yv.w * wv[3];
        }
    }

    // cross-thread d-reduction: red[8][128] f32 (4 KB, reuse smem)
    __syncthreads();
    float* red = (float*)smem;
    *reinterpret_cast<float4*>(red + dsb * 128 + n4) =
        make_float4(part[0], part[1], part[2], part[3]);
    __syncthreads();
    if (tid < 128) {
        float sum = 0.f;
#pragma unroll
        for (int j = 0; j < 8; ++j)
            sum += red[j * 128 + tid];
        atomicAdd(out + n0 + tid, sum);
    }
}

extern "C" void kernel_launch(void* const* d_in, const int* in_sizes, int n_in,
                              void* d_out, int out_size, void* d_ws, size_t ws_size,
                              hipStream_t stream) {
    const float* F = (const float*)d_in[0];   // features (N, K)
    const float* W = (const float*)d_in[1];   // w        (D, N)
    const float* E = (const float*)d_in[2];   // E        (K, D)
    const float* B = (const float*)d_in[3];   // b        (D,)
    float* out = (float*)d_out;               // (N,) f32

    unsigned short* ET = (unsigned short*)d_ws;                       // 4 MB
    unsigned short* FB = (unsigned short*)((char*)d_ws + (size_t)D_DIM * K_DIM * 2);  // 8 MB

    (void)hipMemsetAsync(d_out, 0, (size_t)out_size * sizeof(float), stream);
    transpose_E<<<dim3(D_DIM / 64, K_DIM / 64), 256, 0, stream>>>(E, ET);
    convert_F<<<dim3(N_DIM * K_DIM / (256 * 8)), 256, 0, stream>>>(F, FB);
    gemm_fused<<<dim3(N_DIM / 128, D_DIM / 128), 256, 0, stream>>>(FB, W, ET, B, out);
}

// Round 8
// 244.791 us; speedup vs baseline: 1.1412x; 1.1412x over previous
//
#include <hip/hip_runtime.h>

#define N_DIM 8192   // rows of features / columns of w / output length
#define K_DIM 512    // inner dim of features @ E
#define D_DIM 4096   // columns of E / rows of w

typedef __bf16 bf16x8 __attribute__((ext_vector_type(8)));
typedef float  f32x16 __attribute__((ext_vector_type(16)));
typedef unsigned short u16x8 __attribute__((ext_vector_type(8)));

__device__ __forceinline__ unsigned short f2bf(float f) {
    union { float f; unsigned int u; } v; v.f = f;
    unsigned int r = v.u + 0x7FFF + ((v.u >> 16) & 1);   // RNE
    return (unsigned short)(r >> 16);
}

// ---------------------------------------------------------------------------
// Kernel 1: E [512][4096] f32 -> ETf bf16 in FRAGMENT-MAJOR layout:
// frag(d,k) = (d>>5)*32 + (k>>4); within frag, lane = ((k>>3)&1)*32 + (d&31)
// holds 8 k-contiguous bf16 at shorts[frag*512 + lane*8]. One 32x32x16 MFMA
// A-fragment = 1 KB contiguous -> af load is a fully-coalesced dwordx4.
// ---------------------------------------------------------------------------
__global__ __launch_bounds__(256) void transpose_E(const float* __restrict__ E,
                                                   unsigned short* __restrict__ ETf) {
    __shared__ float tile[64][65];    // [k_local][d_local]
    const int d0 = blockIdx.x * 64;
    const int k0 = blockIdx.y * 64;
    const int tid = threadIdx.x;
    {
        const int r  = tid / 16;          // 0..15
        const int c4 = (tid % 16) * 4;    // 0..60
#pragma unroll
        for (int p = 0; p < 4; ++p) {
            int k = p * 16 + r;
            float4 v = *reinterpret_cast<const float4*>(E + (size_t)(k0 + k) * D_DIM + d0 + c4);
            tile[k][c4 + 0] = v.x; tile[k][c4 + 1] = v.y;
            tile[k][c4 + 2] = v.z; tile[k][c4 + 3] = v.w;
        }
    }
    __syncthreads();
    const int lane = tid & 63;
    const int w    = tid >> 6;        // k16-frag within tile (0..3)
    const int dl5  = lane & 31;
    const int k8h  = lane >> 5;
#pragma unroll
    for (int q = 0; q < 2; ++q) {     // d-half of tile
        u16x8 o;
#pragma unroll
        for (int j = 0; j < 8; ++j)
            o[j] = f2bf(tile[w * 16 + k8h * 8 + j][q * 32 + dl5]);
        const int frag = ((d0 >> 5) + q) * 32 + (k0 >> 4) + w;
        *reinterpret_cast<u16x8*>(ETf + (size_t)frag * 512 + lane * 8) = o;
    }
}

// ---------------------------------------------------------------------------
// Kernel 2: F [8192][512] f32 -> FB bf16, same layout (k-contiguous rows)
// ---------------------------------------------------------------------------
__global__ __launch_bounds__(256) void convert_F(const float* __restrict__ F,
                                                 unsigned short* __restrict__ FB) {
    const int idx8 = (blockIdx.x * 256 + threadIdx.x) * 8;
    float4 a = *reinterpret_cast<const float4*>(F + idx8);
    float4 b = *reinterpret_cast<const float4*>(F + idx8 + 4);
    u16x8 o;
    o[0] = f2bf(a.x); o[1] = f2bf(a.y); o[2] = f2bf(a.z); o[3] = f2bf(a.w);
    o[4] = f2bf(b.x); o[5] = f2bf(b.y); o[6] = f2bf(b.z); o[7] = f2bf(b.w);
    *reinterpret_cast<u16x8*>(FB + idx8) = o;
}

// ---------------------------------------------------------------------------
// Kernel 3: fused  out[n] = sum_d (F@E + b)[n,d] * w[d,n], computed as y^T.
// R8 hybrid feed: B (FB) staged through 16 KB LDS as R4 (global_load_lds,
// XOR chunk swizzle); A (ETf) read DIRECTLY from global in fragment-major
// layout — one coalesced dwordx4 per af, no Ash, no A-staging, halved LDS
// pipe. XCD-rectangle block swizzle keeps each XCD's ETf+FB slice (4 MB)
// L2-resident. R4 epilogue (scalar nt W loads + shfl + atomics).
// ---------------------------------------------------------------------------
__global__ __launch_bounds__(256) void gemm_fused(const unsigned short* __restrict__ FB,
                                                  const float* __restrict__ W,
                                                  const unsigned short* __restrict__ ETf,
                                                  const float* __restrict__ B,
                                                  float* __restrict__ out) {
    __shared__ unsigned short Bsh[2 * 128 * 32];  // FB tile: 2 k-panels x 128 n-rows (16 KB)

    const int tid  = threadIdx.x;
    const int wave = tid >> 6;
    const int lane = tid & 63;
    const int wy   = wave >> 1;     // d-direction wave coord (0..1)
    const int wx   = wave & 1;      // n-direction wave coord (0..1)
    const int l31  = lane & 31;
    const int half = lane >> 5;

    // --- XCD-rectangle swizzle (bijection on 64x32 tile grid) ---
    const int f   = blockIdx.x + ((int)gridDim.x) * blockIdx.y;
    const int xcd = f & 7;
    const int s   = f >> 3;                        // 0..255 within XCD
    const int ntile = (xcd & 3) * 16 + (s & 15);   // 0..63
    const int dtile = (xcd >> 2) * 16 + (s >> 4);  // 0..31
    const int n0 = ntile * 128;
    const int d0 = dtile * 128;

    f32x16 acc[2][2] = {};   // [mi=d-tile][ni=n-tile]

    // A fragment-major base pointers (per mi), lane chunk folded in
    const unsigned short* pa0 = ETf + (size_t)((d0 >> 5) + wy * 2 + 0) * 16384 + lane * 8;
    const unsigned short* pa1 = ETf + (size_t)((d0 >> 5) + wy * 2 + 1) * 16384 + lane * 8;

    // B staging: one global_load_lds(16B) covers 16 rows x 64 B
    const int srow   = lane >> 2;                               // 0..15
    const int schunk = (((lane & 3) ^ ((srow >> 1) & 3)) * 8);  // swizzled chunk (shorts)

    for (int kt = 0; kt < K_DIM / 64; ++kt) {
        const int kb = kt * 64;
#pragma unroll
        for (int p = 0; p < 2; ++p) {
#pragma unroll
            for (int jj = 0; jj < 2; ++jj) {
                const int j = wave * 2 + jj;   // 0..7 -> 16 rows each
                const unsigned short* gb =
                    FB + (size_t)(n0 + j * 16 + srow) * K_DIM + kb + p * 32 + schunk;
                __builtin_amdgcn_global_load_lds(
                    (const __attribute__((address_space(1))) void*)gb,
                    (__attribute__((address_space(3))) void*)(Bsh + p * 4096 + j * 512),
                    16, 0, 0);
            }
        }
        __syncthreads();

#pragma unroll
        for (int ks = 0; ks < 4; ++ks) {
            const int p = ks >> 1;
            const int c = (ks & 1) * 2 + half;   // 16B chunk index within row
            // A: direct global fragment loads (k16 = kt*4 + ks)
            bf16x8 af[2], bf[2];
            af[0] = *reinterpret_cast<const bf16x8*>(pa0 + (kt * 4 + ks) * 512);
            af[1] = *reinterpret_cast<const bf16x8*>(pa1 + (kt * 4 + ks) * 512);
#pragma unroll
            for (int ni = 0; ni < 2; ++ni) {
                const int R = wx * 64 + ni * 32 + l31;
                const int slot = c ^ ((R >> 1) & 3);
                bf[ni] = *reinterpret_cast<const bf16x8*>(
                    Bsh + p * 4096 + R * 32 + slot * 8);
            }
#pragma unroll
            for (int mi = 0; mi < 2; ++mi)
#pragma unroll
                for (int ni = 0; ni < 2; ++ni)
                    acc[mi][ni] = __builtin_amdgcn_mfma_f32_32x32x16_bf16(
                        mi == 0 ? af[0] : af[1], bf[ni], acc[mi][ni], 0, 0, 0);
        }
        __syncthreads();
    }

    // --- epilogue (R4): C layout 32x32: col(n)=lane&31,
    // row(d)=(reg&3)+8*(reg>>2)+4*half; W read once -> non-temporal.
    const int nb = n0 + wx * 64;
    float part0 = 0.f, part1 = 0.f;
#pragma unroll
    for (int mi = 0; mi < 2; ++mi) {
        const int dbase = d0 + wy * 64 + mi * 32 + 4 * half;
#pragma unroll
        for (int reg = 0; reg < 16; ++reg) {
            const int dd = dbase + (reg & 3) + 8 * (reg >> 2);
            const float bd = B[dd];
            const float* wr = W + (size_t)dd * N_DIM + nb;
            part0 += (acc[mi][0][reg] + bd) * __builtin_nontemporal_load(wr + l31);
            part1 += (acc[mi][1][reg] + bd) * __builtin_nontemporal_load(wr + 32 + l31);
        }
    }
    part0 += __shfl_xor(part0, 32);
    part1 += __shfl_xor(part1, 32);
    if (lane < 32) {
        atomicAdd(out + nb + l31, part0);
        atomicAdd(out + nb + 32 + l31, part1);
    }
}

extern "C" void kernel_launch(void* const* d_in, const int* in_sizes, int n_in,
                              void* d_out, int out_size, void* d_ws, size_t ws_size,
                              hipStream_t stream) {
    const float* F = (const float*)d_in[0];   // features (N, K)
    const float* W = (const float*)d_in[1];   // w        (D, N)
    const float* E = (const float*)d_in[2];   // E        (K, D)
    const float* B = (const float*)d_in[3];   // b        (D,)
    float* out = (float*)d_out;               // (N,) f32

    unsigned short* ETf = (unsigned short*)d_ws;                      // 4 MB, fragment-major
    unsigned short* FB  = (unsigned short*)((char*)d_ws + (size_t)D_DIM * K_DIM * 2);  // 8 MB

    (void)hipMemsetAsync(d_out, 0, (size_t)out_size * sizeof(float), stream);
    transpose_E<<<dim3(D_DIM / 64, K_DIM / 64), 256, 0, stream>>>(E, ETf);
    convert_F<<<dim3(N_DIM * K_DIM / (256 * 8)), 256, 0, stream>>>(F, FB);
    gemm_fused<<<dim3(N_DIM / 128, D_DIM / 128), 256, 0, stream>>>(FB, W, ETf, B, out);
}